// Round 10
// baseline (3073.310 us; speedup 1.0000x reference)
//
#include <hip/hip_runtime.h>
#include <stdint.h>

// Problem dims
#define B_ 4096
#define F_ 2048
#define R_ 8
#define O_ 2048
#define N2 (O_ * F_ * R_)   // 33554432
#define N1 (R_ * F_)        // 16384
#define K2SEL ((uint32_t)(N2 / 2))
#define K1SEL ((uint32_t)(N1 / 2))
#define CAND_CAP (512 * 1024)
#define TIE_CAP2 4096

// ---------------- workspace layout (bytes) ----------------
// 0       : state words (uint32): [0]=prefix16 [1]=rank [2]=T2.cutoff [3]=T2.bits [4]=cand_cnt
// 4096    : w1pt (F*R fp32, 64 KB), w1nt (64 KB)
// 262144  : aph/apl/anh/anl (4 x 16 MB bf16)
// 67371008: bph/bpl/bnh/bnl (4 x 8 MB bf16)   -> total ~96.3 MB (same as verified r8)
// ALIASED into B-plane region (dead before wbuild writes it):
//   67371008 + 0    : h16 (16 replica planes x 65536 bins x 4B = 4 MB)
//   67371008 + 4 MB : candk (512K x 4B = 2 MB)
//   67371008 + 6 MB : candi (2 MB)

__device__ __forceinline__ uint32_t fkey(float s) {
    return __float_as_uint(fabsf(s));   // monotone for non-negative floats
}
__device__ __forceinline__ ushort f2bf(float f) {       // RNE fp32->bf16
    uint32_t u = __float_as_uint(f);
    return (ushort)((u + 0x7FFFu + ((u >> 16) & 1u)) >> 16);
}
__device__ __forceinline__ float bf2f(ushort h) {
    return __uint_as_float(((uint32_t)h) << 16);
}

// ---------------- init: zero 16-replica 16-bit histogram + counters ----------
__global__ void init_kernel(uint32_t* st, uint32_t* h16) {
    int i0 = blockIdx.x * blockDim.x + threadIdx.x;
    int stride = gridDim.x * blockDim.x;
    for (int i = i0; i < 16 * 65536; i += stride) h16[i] = 0;
    if (i0 == 0) st[4] = 0;
}

// ---------------- s2 pass 1: 16-bit-prefix histogram (XCD-spread replicas) ---
__global__ void hist16_kernel(const float* __restrict__ s, uint32_t* __restrict__ h16) {
    int stride = gridDim.x * blockDim.x;
    int i0 = blockIdx.x * blockDim.x + threadIdx.x;
    uint32_t rep = ((uint32_t)blockIdx.x & 15u) << 16;
    const float4* s4 = reinterpret_cast<const float4*>(s);
    for (int i = i0; i < N2 / 4; i += stride) {
        float4 v = s4[i];
        atomicAdd(&h16[rep | (fkey(v.x) >> 16)], 1u);
        atomicAdd(&h16[rep | (fkey(v.y) >> 16)], 1u);
        atomicAdd(&h16[rep | (fkey(v.z) >> 16)], 1u);
        atomicAdd(&h16[rep | (fkey(v.w) >> 16)], 1u);
    }
}

// ---------------- scan 65536 bins from top, find 16-bit prefix + rank --------
__global__ void scan16_kernel(uint32_t* __restrict__ h16, uint32_t* __restrict__ st) {
    __shared__ uint32_t csum[256];
    int t = threadIdx.x;
    int base = t * 256;
    uint32_t sum = 0;
    for (int b = 0; b < 256; ++b) {
        uint32_t tot = 0;
        #pragma unroll
        for (int r = 0; r < 16; ++r) tot += h16[(r << 16) + base + b];
        h16[base + b] = tot;            // stash per-bin total in plane 0
        sum += tot;
    }
    csum[t] = sum;
    __syncthreads();
    if (t == 0) {
        uint32_t K = K2SEL, cum = 0;
        int chunk = 255;
        for (; chunk > 0; --chunk) {
            if (cum + csum[chunk] >= K) break;
            cum += csum[chunk];
        }
        for (int b = 255; b >= 0; --b) {
            uint32_t tot = h16[chunk * 256 + b];
            if (cum + tot >= K) { st[0] = (uint32_t)(chunk * 256 + b); st[1] = K - cum; break; }
            cum += tot;
        }
    }
}

// ---------------- s2 pass 2: compact candidates matching the 16-bit prefix ---
__global__ void compact_kernel(const float* __restrict__ s,
                               const uint32_t* __restrict__ st,
                               uint32_t* __restrict__ cnt,
                               uint32_t* __restrict__ candk, uint32_t* __restrict__ candi) {
    uint32_t pfx = st[0];
    int stride = gridDim.x * blockDim.x;
    int i0 = blockIdx.x * blockDim.x + threadIdx.x;
    const float4* s4 = reinterpret_cast<const float4*>(s);
    for (int i = i0; i < N2 / 4; i += stride) {
        float4 v = s4[i];
        uint32_t b[4] = { fkey(v.x), fkey(v.y), fkey(v.z), fkey(v.w) };
        #pragma unroll
        for (int e = 0; e < 4; ++e) {
            if ((b[e] >> 16) == pfx) {
                uint32_t p = atomicAdd(cnt, 1u);
                if (p < CAND_CAP) { candk[p] = b[e]; candi[p] = (uint32_t)(4 * i + e); }
            }
        }
    }
}

// ---------------- finish: 2 radix passes + ties + index cutoff (1 block) -----
__global__ void finish2_kernel(const uint32_t* __restrict__ candk,
                               const uint32_t* __restrict__ candi,
                               uint32_t* __restrict__ st) {
    __shared__ uint32_t hist[256];
    __shared__ uint32_t tie[TIE_CAP2];
    __shared__ uint32_t sh[4];
    int t = threadIdx.x;
    uint32_t c = st[4]; if (c > CAND_CAP) c = CAND_CAP;
    uint32_t prefix = st[0];
    uint32_t K = st[1];

    for (int p = 0; p < 2; ++p) {
        int shift = 8 - 8 * p;
        hist[t] = 0;
        __syncthreads();
        for (uint32_t i = t; i < c; i += 256) {
            uint32_t k = candk[i];
            if ((k >> (shift + 8)) == prefix) atomicAdd(&hist[(k >> shift) & 255u], 1u);
        }
        __syncthreads();
        if (t == 0) {
            uint32_t cum = 0;
            for (int b = 255; b >= 0; --b) {
                uint32_t hb = hist[b];
                if (cum + hb >= K) { sh[2] = (uint32_t)b; sh[3] = K - cum; break; }
                cum += hb;
            }
        }
        __syncthreads();
        prefix = (prefix << 8) | sh[2];
        K = sh[3];
        __syncthreads();
    }
    uint32_t T = prefix;

    if (t == 0) sh[0] = 0;
    __syncthreads();
    for (uint32_t i = t; i < c; i += 256)
        if (candk[i] == T) {
            uint32_t p = atomicAdd(&sh[0], 1u);
            if (p < TIE_CAP2) tie[p] = candi[i];
        }
    __syncthreads();
    uint32_t tc = sh[0]; if (tc > TIE_CAP2) tc = TIE_CAP2;

    uint32_t lo = 0, hi = (uint32_t)(N2 - 1);
    while (lo < hi) {
        uint32_t mid = lo + (hi - lo + 1) / 2;
        if (t == 0) sh[1] = 0;
        __syncthreads();
        uint32_t local = 0;
        for (uint32_t i = t; i < tc; i += 256) if (tie[i] >= mid) local++;
        if (local) atomicAdd(&sh[1], local);
        __syncthreads();
        uint32_t cv = sh[1];
        __syncthreads();
        if (cv >= K) lo = mid; else hi = mid - 1;
    }
    if (t == 0) { st[2] = lo; st[3] = T; }
}

// ---------------- fused s1 select + masked relu-split transposed w1 ----------
__global__ void s1w1_kernel(const float* __restrict__ s1, const float* __restrict__ w1,
                            float* __restrict__ w1pt, float* __restrict__ w1nt) {
    __shared__ uint32_t keys[N1];      // 64 KB
    __shared__ uint32_t hist[256];
    __shared__ uint32_t tie[1024];
    __shared__ uint32_t sh[4];
    int t = threadIdx.x;
    for (int i = t; i < N1; i += 256) keys[i] = fkey(s1[i]);
    __syncthreads();

    uint32_t prefix = 0, K = K1SEL;
    for (int p = 0; p < 4; ++p) {
        int shift = 24 - 8 * p;
        hist[t] = 0;
        __syncthreads();
        for (int i = t; i < N1; i += 256) {
            uint32_t k = keys[i];
            bool ok = (p == 0) || ((k >> (shift + 8)) == prefix);
            if (ok) atomicAdd(&hist[(k >> shift) & 255u], 1u);
        }
        __syncthreads();
        if (t == 0) {
            uint32_t cum = 0;
            for (int b = 255; b >= 0; --b) {
                uint32_t hb = hist[b];
                if (cum + hb >= K) { sh[2] = (uint32_t)b; sh[3] = K - cum; break; }
                cum += hb;
            }
        }
        __syncthreads();
        prefix = (prefix << 8) | sh[2];
        K = sh[3];
        __syncthreads();
    }
    uint32_t T = prefix;

    if (t == 0) sh[0] = 0;
    __syncthreads();
    for (int i = t; i < N1; i += 256)
        if (keys[i] == T) {
            uint32_t p = atomicAdd(&sh[0], 1u);
            if (p < 1024) tie[p] = (uint32_t)i;
        }
    __syncthreads();
    uint32_t tc = sh[0]; if (tc > 1024) tc = 1024;

    uint32_t lo = 0, hi = (uint32_t)(N1 - 1);
    while (lo < hi) {
        uint32_t mid = lo + (hi - lo + 1) / 2;
        if (t == 0) sh[1] = 0;
        __syncthreads();
        uint32_t local = 0;
        for (uint32_t i = t; i < tc; i += 256) if (tie[i] >= mid) local++;
        if (local) atomicAdd(&sh[1], local);
        __syncthreads();
        uint32_t cv = sh[1];
        __syncthreads();
        if (cv >= K) lo = mid; else hi = mid - 1;
    }
    __syncthreads();

    for (int i = t; i < N1; i += 256) {
        uint32_t k = keys[i];
        bool m = (k > T) || (k == T && (uint32_t)i >= lo);
        float v = m ? w1[i] : 0.0f;
        int r = i >> 11;          // i / F_
        int f = i & (F_ - 1);
        w1pt[f * R_ + r] = fmaxf(v, 0.0f);
        w1nt[f * R_ + r] = fminf(v, 0.0f);
    }
}

// ---------------- split x into relu-parts, bf16 hi/lo (UNCHANGED) ------------
__global__ void xsplit_kernel(const float* __restrict__ x,
                              ushort* __restrict__ ph, ushort* __restrict__ pl,
                              ushort* __restrict__ nh, ushort* __restrict__ nl) {
    int t = blockIdx.x * blockDim.x + threadIdx.x;   // one float4
    float4 v = reinterpret_cast<const float4*>(x)[t];
    float vv[4] = { v.x, v.y, v.z, v.w };
    ushort oph[4], opl[4], onh[4], onl[4];
    #pragma unroll
    for (int e = 0; e < 4; ++e) {
        float p = fmaxf(vv[e], 0.f), n = fminf(vv[e], 0.f);
        ushort h1 = f2bf(p); oph[e] = h1; opl[e] = f2bf(p - bf2f(h1));
        ushort h2 = f2bf(n); onh[e] = h2; onl[e] = f2bf(n - bf2f(h2));
    }
    *reinterpret_cast<ushort4*>(&ph[t * 4]) = make_ushort4(oph[0], oph[1], oph[2], oph[3]);
    *reinterpret_cast<ushort4*>(&pl[t * 4]) = make_ushort4(opl[0], opl[1], opl[2], opl[3]);
    *reinterpret_cast<ushort4*>(&nh[t * 4]) = make_ushort4(onh[0], onh[1], onh[2], onh[3]);
    *reinterpret_cast<ushort4*>(&nl[t * 4]) = make_ushort4(onl[0], onl[1], onl[2], onl[3]);
}

// ---------------- rank-collapse: Wp/Wn[o,f], bf16 hi/lo (UNCHANGED) ----------
__global__ void wbuild_kernel(const float* __restrict__ w2, const float* __restrict__ s2,
                              const uint32_t* __restrict__ T2,
                              const float* __restrict__ w1pt, const float* __restrict__ w1nt,
                              ushort* __restrict__ bph, ushort* __restrict__ bpl,
                              ushort* __restrict__ bnh, ushort* __restrict__ bnl) {
    int t = blockIdx.x * blockDim.x + threadIdx.x;   // t = o*F_ + f
    int f = t & (F_ - 1);
    uint32_t tb = T2[1], tc = T2[0];
    int base = (t >> 11) * (F_ * R_) + f * R_;

    float4 wa = *reinterpret_cast<const float4*>(w2 + base);
    float4 wb = *reinterpret_cast<const float4*>(w2 + base + 4);
    float4 sa = *reinterpret_cast<const float4*>(s2 + base);
    float4 sb = *reinterpret_cast<const float4*>(s2 + base + 4);
    float4 pa = *reinterpret_cast<const float4*>(w1pt + f * R_);
    float4 pb = *reinterpret_cast<const float4*>(w1pt + f * R_ + 4);
    float4 na = *reinterpret_cast<const float4*>(w1nt + f * R_);
    float4 nb = *reinterpret_cast<const float4*>(w1nt + f * R_ + 4);

    float wv[8] = { wa.x, wa.y, wa.z, wa.w, wb.x, wb.y, wb.z, wb.w };
    float sv[8] = { sa.x, sa.y, sa.z, sa.w, sb.x, sb.y, sb.z, sb.w };
    float pv[8] = { pa.x, pa.y, pa.z, pa.w, pb.x, pb.y, pb.z, pb.w };
    float nv[8] = { na.x, na.y, na.z, na.w, nb.x, nb.y, nb.z, nb.w };

    float accp = 0.f, accn = 0.f;
    #pragma unroll
    for (int r = 0; r < 8; ++r) {
        uint32_t kb = fkey(sv[r]);
        bool m = (kb > tb) || (kb == tb && (uint32_t)(base + r) >= tc);
        float wm = m ? wv[r] : 0.0f;
        accp = fmaf(pv[r], wm, accp);
        accn = fmaf(nv[r], wm, accn);
    }
    ushort h1 = f2bf(accp); bph[t] = h1; bpl[t] = f2bf(accp - bf2f(h1));
    ushort h2 = f2bf(accn); bnh[t] = h2; bnl[t] = f2bf(accn - bf2f(h2));
}

// ---------------- split-bf16 MFMA GEMM (UNCHANGED, verified r8) --------------
typedef __attribute__((ext_vector_type(8))) short bf16x8;
typedef __attribute__((ext_vector_type(4))) float f32x4;

__device__ __forceinline__ void gload16(const void* g, void* l) {
    __builtin_amdgcn_global_load_lds((const __attribute__((address_space(1))) void*)g,
                                     (__attribute__((address_space(3))) void*)l, 16, 0, 0);
}

__global__ __launch_bounds__(256) void mfma_gemm(
    const ushort* __restrict__ aph, const ushort* __restrict__ apl,
    const ushort* __restrict__ anh, const ushort* __restrict__ anl,
    const ushort* __restrict__ bph, const ushort* __restrict__ bpl,
    const ushort* __restrict__ bnh, const ushort* __restrict__ bnl,
    float* __restrict__ out) {
    __shared__ ushort lds[4][128][32];

    const int tid  = threadIdx.x;
    const int wid  = tid >> 6;
    const int lane = tid & 63;
    const int brow = blockIdx.y * 128;
    const int bcol = blockIdx.x * 128;
    const int wr = (wid >> 1) * 64;
    const int wc = (wid & 1) * 64;

    f32x4 acc[4][4] = {};

    const int srow = lane >> 2;
    const int scol = (lane & 3) * 8;

    #pragma unroll 1
    for (int plane = 0; plane < 2; ++plane) {
        const ushort* tsrc =
            (wid == 0) ? (plane ? anh : aph) :
            (wid == 1) ? (plane ? anl : apl) :
            (wid == 2) ? (plane ? bnh : bph) :
                         (plane ? bnl : bpl);
        const int rowbase = (wid < 2) ? brow : bcol;

        #pragma unroll 1
        for (int k0 = 0; k0 < F_; k0 += 32) {
            #pragma unroll
            for (int t = 0; t < 8; ++t) {
                const ushort* g = tsrc + (size_t)(rowbase + t * 16 + srow) * F_ + k0 + scol;
                gload16(g, (void*)&lds[wid][t * 16][0]);
            }
            __syncthreads();

            bf16x8 ah[4], al[4], bh[4], bl[4];
            const int fr = lane & 15;
            const int kc = (lane >> 4) * 8;
            #pragma unroll
            for (int i = 0; i < 4; ++i) {
                ah[i] = *(const bf16x8*)&lds[0][wr + i * 16 + fr][kc];
                al[i] = *(const bf16x8*)&lds[1][wr + i * 16 + fr][kc];
                bh[i] = *(const bf16x8*)&lds[2][wc + i * 16 + fr][kc];
                bl[i] = *(const bf16x8*)&lds[3][wc + i * 16 + fr][kc];
            }
            #pragma unroll
            for (int i = 0; i < 4; ++i)
                #pragma unroll
                for (int j = 0; j < 4; ++j) {
                    acc[i][j] = __builtin_amdgcn_mfma_f32_16x16x32_bf16(ah[i], bh[j], acc[i][j], 0, 0, 0);
                    acc[i][j] = __builtin_amdgcn_mfma_f32_16x16x32_bf16(ah[i], bl[j], acc[i][j], 0, 0, 0);
                    acc[i][j] = __builtin_amdgcn_mfma_f32_16x16x32_bf16(al[i], bh[j], acc[i][j], 0, 0, 0);
                }
            __syncthreads();
        }
    }

    #pragma unroll
    for (int i = 0; i < 4; ++i) {
        int orow0 = brow + wr + i * 16 + (lane >> 4) * 4;
        #pragma unroll
        for (int j = 0; j < 4; ++j) {
            int ocol = bcol + wc + j * 16 + (lane & 15);
            #pragma unroll
            for (int q = 0; q < 4; ++q)
                out[(size_t)(orow0 + q) * O_ + ocol] = acc[i][j][q];
        }
    }
}

extern "C" void kernel_launch(void* const* d_in, const int* in_sizes, int n_in,
                              void* d_out, int out_size, void* d_ws, size_t ws_size,
                              hipStream_t stream) {
    const float* x  = (const float*)d_in[0];
    const float* w1 = (const float*)d_in[1];
    const float* w2 = (const float*)d_in[2];
    const float* s1 = (const float*)d_in[3];
    const float* s2 = (const float*)d_in[4];
    float* out = (float*)d_out;

    uint32_t* st = (uint32_t*)d_ws;

    float* w1pt = (float*)((char*)d_ws + 4096);
    float* w1nt = w1pt + N1;

    char* baseA = (char*)d_ws + 262144;
    ushort* aph = (ushort*)baseA;
    ushort* apl = aph + (size_t)B_ * F_;
    ushort* anh = apl + (size_t)B_ * F_;
    ushort* anl = anh + (size_t)B_ * F_;
    ushort* bph = anl + (size_t)B_ * F_;         // byte 67371008
    ushort* bpl = bph + (size_t)O_ * F_;
    ushort* bnh = bpl + (size_t)O_ * F_;
    ushort* bnl = bnh + (size_t)O_ * F_;

    // select scratch ALIASES the B-plane region (dead before wbuild writes)
    uint32_t* h16   = (uint32_t*)((char*)d_ws + 67371008);
    uint32_t* candk = (uint32_t*)((char*)d_ws + 67371008 + (4u << 20));
    uint32_t* candi = (uint32_t*)((char*)d_ws + 67371008 + (6u << 20));

    init_kernel<<<1024, 256, 0, stream>>>(st, h16);

    xsplit_kernel<<<(B_ * F_ / 4) / 256, 256, 0, stream>>>(x, aph, apl, anh, anl);

    // s2 exact top-half threshold: 2 full scans + 2 small kernels
    hist16_kernel<<<2048, 256, 0, stream>>>(s2, h16);
    scan16_kernel<<<1, 256, 0, stream>>>(h16, st);
    compact_kernel<<<2048, 256, 0, stream>>>(s2, st, &st[4], candk, candi);
    finish2_kernel<<<1, 256, 0, stream>>>(candk, candi, st);

    // s1 select + w1 transform fused, single block
    s1w1_kernel<<<1, 256, 0, stream>>>(s1, w1, w1pt, w1nt);

    // rank-collapse -> bf16 hi/lo weight planes (reads T2 = st+2)
    wbuild_kernel<<<(O_ * F_) / 256, 256, 0, stream>>>(w2, s2, &st[2], w1pt, w1nt,
                                                       bph, bpl, bnh, bnl);

    // split-bf16 MFMA GEMM
    mfma_gemm<<<dim3(O_ / 128, B_ / 128), 256, 0, stream>>>(
        aph, apl, anh, anl, bph, bpl, bnh, bnl, out);
}

// Round 13
// 967.161 us; speedup vs baseline: 3.1777x; 3.1777x over previous
//
#include <hip/hip_runtime.h>
#include <stdint.h>

// Problem dims
#define B_ 4096
#define F_ 2048
#define R_ 8
#define O_ 2048
#define N2 (O_ * F_ * R_)   // 33554432
#define N1 (R_ * F_)        // 16384
#define K2SEL ((uint32_t)(N2 / 2))
#define K1SEL ((uint32_t)(N1 / 2))
#define CAND_CAP (512 * 1024)
#define TIE_CAP2 4096
#define HB 32768            // 16-bit prefix bins (sign bit always 0)
#define HPLANES 256
#define CBUF 4096

// ---------------- workspace layout (bytes) ----------------
// 0      : st words: [0]=prefix16 [1]=rank [2]=T2.cutoff [3]=T2.bits [4]=cand_cnt
// 4096   : w1pt (64 KB), w1nt (64 KB)
// 262144 : A planes aph/apl/anh/anl (4 x 16 MB)  -- written by xsplit AFTER selection
//   scratch aliased into A region (dead before xsplit):
//   +0 MB : hplanes (256 x 32768 x 4B = 32 MB)
//   +32MB : candk (2 MB)   +34MB : candi (2 MB)   +36MB : total (128 KB)
// 67371008: B planes bph/bpl/bnh/bnl (4 x 8 MB)  -> ~96.3 MB total (as verified r8)

__device__ __forceinline__ uint32_t fkey(float s) {
    return __float_as_uint(fabsf(s));   // monotone for non-negative floats
}
__device__ __forceinline__ ushort f2bf(float f) {       // RNE fp32->bf16
    uint32_t u = __float_as_uint(f);
    return (ushort)((u + 0x7FFFu + ((u >> 16) & 1u)) >> 16);
}
__device__ __forceinline__ float bf2f(ushort h) {
    return __uint_as_float(((uint32_t)h) << 16);
}

// ---------------- init: zero candidate counter only --------------------------
__global__ void init_kernel(uint32_t* st) {
    if (threadIdx.x == 0 && blockIdx.x == 0) st[4] = 0;
}

// ---------------- s2 pass 1: LDS 16-bit-prefix histogram, store plane --------
__global__ __launch_bounds__(256) void hist16_kernel(const float* __restrict__ s,
                                                     uint32_t* __restrict__ hplanes) {
    __shared__ uint32_t h[HB];          // 128 KB
    for (int i = threadIdx.x; i < HB; i += 256) h[i] = 0;
    __syncthreads();

    const float4* s4 = reinterpret_cast<const float4*>(s);
    int stride = gridDim.x * blockDim.x;
    for (int i = blockIdx.x * blockDim.x + threadIdx.x; i < N2 / 4; i += stride) {
        float4 v = s4[i];
        atomicAdd(&h[fkey(v.x) >> 16], 1u);
        atomicAdd(&h[fkey(v.y) >> 16], 1u);
        atomicAdd(&h[fkey(v.z) >> 16], 1u);
        atomicAdd(&h[fkey(v.w) >> 16], 1u);
    }
    __syncthreads();

    uint32_t* plane = hplanes + (size_t)blockIdx.x * HB;
    for (int i = threadIdx.x; i < HB; i += 256) plane[i] = h[i];   // plain stores
}

// ---------------- parallel plane reduce: total[bin] --------------------------
__global__ void hreduce_kernel(const uint32_t* __restrict__ hplanes,
                               uint32_t* __restrict__ total) {
    int b = blockIdx.x * blockDim.x + threadIdx.x;   // 0..HB-1
    uint32_t sum = 0;
    #pragma unroll 8
    for (int p = 0; p < HPLANES; ++p) sum += hplanes[(size_t)p * HB + b];
    total[b] = sum;
}

// ---------------- scan 32768 bins from top, find 16-bit prefix + rank --------
__global__ void scan16_kernel(const uint32_t* __restrict__ total, uint32_t* __restrict__ st) {
    __shared__ uint32_t csum[256];
    int t = threadIdx.x;
    uint32_t sum = 0;
    for (int b = 0; b < HB / 256; ++b) sum += total[t * (HB / 256) + b];
    csum[t] = sum;
    __syncthreads();
    if (t == 0) {
        uint32_t K = K2SEL, cum = 0;
        int chunk = 255;
        for (; chunk > 0; --chunk) {
            if (cum + csum[chunk] >= K) break;
            cum += csum[chunk];
        }
        for (int b = HB / 256 - 1; b >= 0; --b) {
            uint32_t tot = total[chunk * (HB / 256) + b];
            if (cum + tot >= K) { st[0] = (uint32_t)(chunk * (HB / 256) + b); st[1] = K - cum; break; }
            cum += tot;
        }
    }
}

// ---------------- s2 pass 2: compact candidates (block-buffered) -------------
__global__ __launch_bounds__(256) void compact_kernel(const float* __restrict__ s,
                                                      const uint32_t* __restrict__ st,
                                                      uint32_t* __restrict__ cnt,
                                                      uint32_t* __restrict__ candk,
                                                      uint32_t* __restrict__ candi) {
    __shared__ uint32_t bk[CBUF], bi[CBUF];
    __shared__ uint32_t bn, base;
    if (threadIdx.x == 0) bn = 0;
    __syncthreads();

    uint32_t pfx = st[0];
    const float4* s4 = reinterpret_cast<const float4*>(s);
    int stride = gridDim.x * blockDim.x;
    for (int i = blockIdx.x * blockDim.x + threadIdx.x; i < N2 / 4; i += stride) {
        float4 v = s4[i];
        uint32_t b[4] = { fkey(v.x), fkey(v.y), fkey(v.z), fkey(v.w) };
        #pragma unroll
        for (int e = 0; e < 4; ++e) {
            if ((b[e] >> 16) == pfx) {
                uint32_t p = atomicAdd(&bn, 1u);
                if (p < CBUF) { bk[p] = b[e]; bi[p] = (uint32_t)(4 * i + e); }
            }
        }
    }
    __syncthreads();
    if (threadIdx.x == 0) {
        uint32_t n = bn; if (n > CBUF) n = CBUF;
        base = atomicAdd(cnt, n);                    // ONE global atomic per block
    }
    __syncthreads();
    uint32_t n = bn; if (n > CBUF) n = CBUF;
    for (uint32_t p = threadIdx.x; p < n; p += 256) {
        uint32_t g = base + p;
        if (g < CAND_CAP) { candk[g] = bk[p]; candi[g] = bi[p]; }
    }
}

// ---------------- finish: 2 radix passes + ties + index cutoff (1 block) -----
__global__ void finish2_kernel(const uint32_t* __restrict__ candk,
                               const uint32_t* __restrict__ candi,
                               uint32_t* __restrict__ st) {
    __shared__ uint32_t hist[256];
    __shared__ uint32_t tie[TIE_CAP2];
    __shared__ uint32_t sh[4];
    int t = threadIdx.x;
    uint32_t c = st[4]; if (c > CAND_CAP) c = CAND_CAP;
    uint32_t prefix = st[0];
    uint32_t K = st[1];

    for (int p = 0; p < 2; ++p) {
        int shift = 8 - 8 * p;
        hist[t] = 0;
        __syncthreads();
        for (uint32_t i = t; i < c; i += 256) {
            uint32_t k = candk[i];
            if ((k >> (shift + 8)) == prefix) atomicAdd(&hist[(k >> shift) & 255u], 1u);
        }
        __syncthreads();
        if (t == 0) {
            uint32_t cum = 0;
            for (int b = 255; b >= 0; --b) {
                uint32_t hb = hist[b];
                if (cum + hb >= K) { sh[2] = (uint32_t)b; sh[3] = K - cum; break; }
                cum += hb;
            }
        }
        __syncthreads();
        prefix = (prefix << 8) | sh[2];
        K = sh[3];
        __syncthreads();
    }
    uint32_t T = prefix;

    if (t == 0) sh[0] = 0;
    __syncthreads();
    for (uint32_t i = t; i < c; i += 256)
        if (candk[i] == T) {
            uint32_t p = atomicAdd(&sh[0], 1u);
            if (p < TIE_CAP2) tie[p] = candi[i];
        }
    __syncthreads();
    uint32_t tc = sh[0]; if (tc > TIE_CAP2) tc = TIE_CAP2;

    uint32_t lo = 0, hi = (uint32_t)(N2 - 1);
    while (lo < hi) {
        uint32_t mid = lo + (hi - lo + 1) / 2;
        if (t == 0) sh[1] = 0;
        __syncthreads();
        uint32_t local = 0;
        for (uint32_t i = t; i < tc; i += 256) if (tie[i] >= mid) local++;
        if (local) atomicAdd(&sh[1], local);
        __syncthreads();
        uint32_t cv = sh[1];
        __syncthreads();
        if (cv >= K) lo = mid; else hi = mid - 1;
    }
    if (t == 0) { st[2] = lo; st[3] = T; }
}

// ---------------- fused s1 select + masked relu-split transposed w1 ----------
__global__ void s1w1_kernel(const float* __restrict__ s1, const float* __restrict__ w1,
                            float* __restrict__ w1pt, float* __restrict__ w1nt) {
    __shared__ uint32_t keys[N1];      // 64 KB
    __shared__ uint32_t hist[256];
    __shared__ uint32_t tie[1024];
    __shared__ uint32_t sh[4];
    int t = threadIdx.x;
    for (int i = t; i < N1; i += 256) keys[i] = fkey(s1[i]);
    __syncthreads();

    uint32_t prefix = 0, K = K1SEL;
    for (int p = 0; p < 4; ++p) {
        int shift = 24 - 8 * p;
        hist[t] = 0;
        __syncthreads();
        for (int i = t; i < N1; i += 256) {
            uint32_t k = keys[i];
            bool ok = (p == 0) || ((k >> (shift + 8)) == prefix);
            if (ok) atomicAdd(&hist[(k >> shift) & 255u], 1u);
        }
        __syncthreads();
        if (t == 0) {
            uint32_t cum = 0;
            for (int b = 255; b >= 0; --b) {
                uint32_t hb = hist[b];
                if (cum + hb >= K) { sh[2] = (uint32_t)b; sh[3] = K - cum; break; }
                cum += hb;
            }
        }
        __syncthreads();
        prefix = (prefix << 8) | sh[2];
        K = sh[3];
        __syncthreads();
    }
    uint32_t T = prefix;

    if (t == 0) sh[0] = 0;
    __syncthreads();
    for (int i = t; i < N1; i += 256)
        if (keys[i] == T) {
            uint32_t p = atomicAdd(&sh[0], 1u);
            if (p < 1024) tie[p] = (uint32_t)i;
        }
    __syncthreads();
    uint32_t tc = sh[0]; if (tc > 1024) tc = 1024;

    uint32_t lo = 0, hi = (uint32_t)(N1 - 1);
    while (lo < hi) {
        uint32_t mid = lo + (hi - lo + 1) / 2;
        if (t == 0) sh[1] = 0;
        __syncthreads();
        uint32_t local = 0;
        for (uint32_t i = t; i < tc; i += 256) if (tie[i] >= mid) local++;
        if (local) atomicAdd(&sh[1], local);
        __syncthreads();
        uint32_t cv = sh[1];
        __syncthreads();
        if (cv >= K) lo = mid; else hi = mid - 1;
    }
    __syncthreads();

    for (int i = t; i < N1; i += 256) {
        uint32_t k = keys[i];
        bool m = (k > T) || (k == T && (uint32_t)i >= lo);
        float v = m ? w1[i] : 0.0f;
        int r = i >> 11;          // i / F_
        int f = i & (F_ - 1);
        w1pt[f * R_ + r] = fmaxf(v, 0.0f);
        w1nt[f * R_ + r] = fminf(v, 0.0f);
    }
}

// ---------------- split x into relu-parts, bf16 hi/lo (UNCHANGED) ------------
__global__ void xsplit_kernel(const float* __restrict__ x,
                              ushort* __restrict__ ph, ushort* __restrict__ pl,
                              ushort* __restrict__ nh, ushort* __restrict__ nl) {
    int t = blockIdx.x * blockDim.x + threadIdx.x;   // one float4
    float4 v = reinterpret_cast<const float4*>(x)[t];
    float vv[4] = { v.x, v.y, v.z, v.w };
    ushort oph[4], opl[4], onh[4], onl[4];
    #pragma unroll
    for (int e = 0; e < 4; ++e) {
        float p = fmaxf(vv[e], 0.f), n = fminf(vv[e], 0.f);
        ushort h1 = f2bf(p); oph[e] = h1; opl[e] = f2bf(p - bf2f(h1));
        ushort h2 = f2bf(n); onh[e] = h2; onl[e] = f2bf(n - bf2f(h2));
    }
    *reinterpret_cast<ushort4*>(&ph[t * 4]) = make_ushort4(oph[0], oph[1], oph[2], oph[3]);
    *reinterpret_cast<ushort4*>(&pl[t * 4]) = make_ushort4(opl[0], opl[1], opl[2], opl[3]);
    *reinterpret_cast<ushort4*>(&nh[t * 4]) = make_ushort4(onh[0], onh[1], onh[2], onh[3]);
    *reinterpret_cast<ushort4*>(&nl[t * 4]) = make_ushort4(onl[0], onl[1], onl[2], onl[3]);
}

// ---------------- rank-collapse: Wp/Wn[o,f], bf16 hi/lo (UNCHANGED) ----------
__global__ void wbuild_kernel(const float* __restrict__ w2, const float* __restrict__ s2,
                              const uint32_t* __restrict__ T2,
                              const float* __restrict__ w1pt, const float* __restrict__ w1nt,
                              ushort* __restrict__ bph, ushort* __restrict__ bpl,
                              ushort* __restrict__ bnh, ushort* __restrict__ bnl) {
    int t = blockIdx.x * blockDim.x + threadIdx.x;   // t = o*F_ + f
    int f = t & (F_ - 1);
    uint32_t tb = T2[1], tc = T2[0];
    int base = (t >> 11) * (F_ * R_) + f * R_;

    float4 wa = *reinterpret_cast<const float4*>(w2 + base);
    float4 wb = *reinterpret_cast<const float4*>(w2 + base + 4);
    float4 sa = *reinterpret_cast<const float4*>(s2 + base);
    float4 sb = *reinterpret_cast<const float4*>(s2 + base + 4);
    float4 pa = *reinterpret_cast<const float4*>(w1pt + f * R_);
    float4 pb = *reinterpret_cast<const float4*>(w1pt + f * R_ + 4);
    float4 na = *reinterpret_cast<const float4*>(w1nt + f * R_);
    float4 nb = *reinterpret_cast<const float4*>(w1nt + f * R_ + 4);

    float wv[8] = { wa.x, wa.y, wa.z, wa.w, wb.x, wb.y, wb.z, wb.w };
    float sv[8] = { sa.x, sa.y, sa.z, sa.w, sb.x, sb.y, sb.z, sb.w };
    float pv[8] = { pa.x, pa.y, pa.z, pa.w, pb.x, pb.y, pb.z, pb.w };
    float nv[8] = { na.x, na.y, na.z, na.w, nb.x, nb.y, nb.z, nb.w };

    float accp = 0.f, accn = 0.f;
    #pragma unroll
    for (int r = 0; r < 8; ++r) {
        uint32_t kb = fkey(sv[r]);
        bool m = (kb > tb) || (kb == tb && (uint32_t)(base + r) >= tc);
        float wm = m ? wv[r] : 0.0f;
        accp = fmaf(pv[r], wm, accp);
        accn = fmaf(nv[r], wm, accn);
    }
    ushort h1 = f2bf(accp); bph[t] = h1; bpl[t] = f2bf(accp - bf2f(h1));
    ushort h2 = f2bf(accn); bnh[t] = h2; bnl[t] = f2bf(accn - bf2f(h2));
}

// ---------------- split-bf16 MFMA GEMM (UNCHANGED, verified r8) --------------
typedef __attribute__((ext_vector_type(8))) short bf16x8;
typedef __attribute__((ext_vector_type(4))) float f32x4;

__device__ __forceinline__ void gload16(const void* g, void* l) {
    __builtin_amdgcn_global_load_lds((const __attribute__((address_space(1))) void*)g,
                                     (__attribute__((address_space(3))) void*)l, 16, 0, 0);
}

__global__ __launch_bounds__(256) void mfma_gemm(
    const ushort* __restrict__ aph, const ushort* __restrict__ apl,
    const ushort* __restrict__ anh, const ushort* __restrict__ anl,
    const ushort* __restrict__ bph, const ushort* __restrict__ bpl,
    const ushort* __restrict__ bnh, const ushort* __restrict__ bnl,
    float* __restrict__ out) {
    __shared__ ushort lds[4][128][32];

    const int tid  = threadIdx.x;
    const int wid  = tid >> 6;
    const int lane = tid & 63;
    const int brow = blockIdx.y * 128;
    const int bcol = blockIdx.x * 128;
    const int wr = (wid >> 1) * 64;
    const int wc = (wid & 1) * 64;

    f32x4 acc[4][4] = {};

    const int srow = lane >> 2;
    const int scol = (lane & 3) * 8;

    #pragma unroll 1
    for (int plane = 0; plane < 2; ++plane) {
        const ushort* tsrc =
            (wid == 0) ? (plane ? anh : aph) :
            (wid == 1) ? (plane ? anl : apl) :
            (wid == 2) ? (plane ? bnh : bph) :
                         (plane ? bnl : bpl);
        const int rowbase = (wid < 2) ? brow : bcol;

        #pragma unroll 1
        for (int k0 = 0; k0 < F_; k0 += 32) {
            #pragma unroll
            for (int t = 0; t < 8; ++t) {
                const ushort* g = tsrc + (size_t)(rowbase + t * 16 + srow) * F_ + k0 + scol;
                gload16(g, (void*)&lds[wid][t * 16][0]);
            }
            __syncthreads();

            bf16x8 ah[4], al[4], bh[4], bl[4];
            const int fr = lane & 15;
            const int kc = (lane >> 4) * 8;
            #pragma unroll
            for (int i = 0; i < 4; ++i) {
                ah[i] = *(const bf16x8*)&lds[0][wr + i * 16 + fr][kc];
                al[i] = *(const bf16x8*)&lds[1][wr + i * 16 + fr][kc];
                bh[i] = *(const bf16x8*)&lds[2][wc + i * 16 + fr][kc];
                bl[i] = *(const bf16x8*)&lds[3][wc + i * 16 + fr][kc];
            }
            #pragma unroll
            for (int i = 0; i < 4; ++i)
                #pragma unroll
                for (int j = 0; j < 4; ++j) {
                    acc[i][j] = __builtin_amdgcn_mfma_f32_16x16x32_bf16(ah[i], bh[j], acc[i][j], 0, 0, 0);
                    acc[i][j] = __builtin_amdgcn_mfma_f32_16x16x32_bf16(ah[i], bl[j], acc[i][j], 0, 0, 0);
                    acc[i][j] = __builtin_amdgcn_mfma_f32_16x16x32_bf16(al[i], bh[j], acc[i][j], 0, 0, 0);
                }
            __syncthreads();
        }
    }

    #pragma unroll
    for (int i = 0; i < 4; ++i) {
        int orow0 = brow + wr + i * 16 + (lane >> 4) * 4;
        #pragma unroll
        for (int j = 0; j < 4; ++j) {
            int ocol = bcol + wc + j * 16 + (lane & 15);
            #pragma unroll
            for (int q = 0; q < 4; ++q)
                out[(size_t)(orow0 + q) * O_ + ocol] = acc[i][j][q];
        }
    }
}

extern "C" void kernel_launch(void* const* d_in, const int* in_sizes, int n_in,
                              void* d_out, int out_size, void* d_ws, size_t ws_size,
                              hipStream_t stream) {
    const float* x  = (const float*)d_in[0];
    const float* w1 = (const float*)d_in[1];
    const float* w2 = (const float*)d_in[2];
    const float* s1 = (const float*)d_in[3];
    const float* s2 = (const float*)d_in[4];
    float* out = (float*)d_out;

    uint32_t* st = (uint32_t*)d_ws;

    float* w1pt = (float*)((char*)d_ws + 4096);
    float* w1nt = w1pt + N1;

    char* abase = (char*)d_ws + 262144;
    ushort* aph = (ushort*)abase;
    ushort* apl = aph + (size_t)B_ * F_;
    ushort* anh = apl + (size_t)B_ * F_;
    ushort* anl = anh + (size_t)B_ * F_;
    ushort* bph = anl + (size_t)B_ * F_;         // byte 67371008
    ushort* bpl = bph + (size_t)O_ * F_;
    ushort* bnh = bpl + (size_t)O_ * F_;
    ushort* bnl = bnh + (size_t)O_ * F_;

    // selection scratch ALIASES the A-plane region (xsplit runs after selection)
    uint32_t* hplanes = (uint32_t*)abase;                        // 32 MB
    uint32_t* candk   = (uint32_t*)(abase + (32u << 20));        // 2 MB
    uint32_t* candi   = (uint32_t*)(abase + (34u << 20));        // 2 MB
    uint32_t* total   = (uint32_t*)(abase + (36u << 20));        // 128 KB

    init_kernel<<<1, 64, 0, stream>>>(st);

    // s2 exact top-half threshold: 2 full scans, LDS histograms, no hot atomics
    hist16_kernel<<<HPLANES, 256, 0, stream>>>(s2, hplanes);
    hreduce_kernel<<<HB / 256, 256, 0, stream>>>(hplanes, total);
    scan16_kernel<<<1, 256, 0, stream>>>(total, st);
    compact_kernel<<<2048, 256, 0, stream>>>(s2, st, &st[4], candk, candi);
    finish2_kernel<<<1, 256, 0, stream>>>(candk, candi, st);

    // s1 select + w1 transform fused, single block
    s1w1_kernel<<<1, 256, 0, stream>>>(s1, w1, w1pt, w1nt);

    // x split (now AFTER selection so scratch aliasing is safe)
    xsplit_kernel<<<(B_ * F_ / 4) / 256, 256, 0, stream>>>(x, aph, apl, anh, anl);

    // rank-collapse -> bf16 hi/lo weight planes (reads T2 = st+2)
    wbuild_kernel<<<(O_ * F_) / 256, 256, 0, stream>>>(w2, s2, &st[2], w1pt, w1nt,
                                                       bph, bpl, bnh, bnl);

    // split-bf16 MFMA GEMM
    mfma_gemm<<<dim3(O_ / 128, B_ / 128), 256, 0, stream>>>(
        aph, apl, anh, anl, bph, bpl, bnh, bnl, out);
}